// Round 4
// baseline (593.189 us; speedup 1.0000x reference)
//
#include <hip/hip_runtime.h>

#define NN 100000
#define DD 512
#define HH 256
#define KNB 5

typedef __attribute__((ext_vector_type(8))) short short8v;
typedef __attribute__((ext_vector_type(4))) short short4v;
typedef __attribute__((ext_vector_type(4))) float float4v;

static __device__ __forceinline__ float bf2f(unsigned short u) {
  union { unsigned int i; float f; } c;
  c.i = ((unsigned int)u) << 16;
  return c.f;
}
static __device__ __forceinline__ unsigned short f2bf(float f) {
  union { float f; unsigned int i; } c;
  c.f = f;
  unsigned int u = c.i;
  u += 0x7FFFu + ((u >> 16) & 1u);   // round-to-nearest-even
  return (unsigned short)(u >> 16);
}

// async global->LDS, 16B per lane; lds dest base must be wave-uniform
#define GLOAD16(g, l) __builtin_amdgcn_global_load_lds( \
    (const __attribute__((address_space(1))) unsigned int*)(g), \
    (__attribute__((address_space(3))) unsigned int*)(l), 16, 0, 0)

// bf16 conversion of the two input-projection weights
__global__ void cvt2(const float* __restrict__ s0, short* __restrict__ d0,
                     const float* __restrict__ s1, short* __restrict__ d1) {
  const int S1 = (HH * DD) / 4;
  int i = blockIdx.x * blockDim.x + threadIdx.x;
  if (i >= 2 * S1) return;
  const float* s = (i < S1) ? s0 : s1;
  short* d = (i < S1) ? d0 : d1;
  int j = (i < S1) ? i : i - S1;
  float4 v = reinterpret_cast<const float4*>(s)[j];
  short4v o;
  o[0] = (short)f2bf(v.x); o[1] = (short)f2bf(v.y);
  o[2] = (short)f2bf(v.z); o[3] = (short)f2bf(v.w);
  reinterpret_cast<short4v*>(d)[j] = o;
}

// Bcat [256][768] = [w0 | W01=w1@w0 | w2] bf16; bc[i] = b0+b1+b2 + w1@b0 (fp32)
__global__ void prep_w01(const float* __restrict__ w0, const float* __restrict__ w1,
                         const float* __restrict__ w2, const float* __restrict__ b0,
                         const float* __restrict__ b1, const float* __restrict__ b2,
                         short* __restrict__ Bcat, float* __restrict__ bc) {
  int i = blockIdx.x;      // output row 0..255
  int j = threadIdx.x;     // col 0..255
  Bcat[(size_t)i * 768 + j]       = (short)f2bf(w0[i * 256 + j]);
  Bcat[(size_t)i * 768 + 512 + j] = (short)f2bf(w2[i * 256 + j]);
  float acc = 0.f;
  for (int k = 0; k < 256; ++k)
    acc = fmaf(w1[i * 256 + k], w0[k * 256 + j], acc);
  Bcat[(size_t)i * 768 + 256 + j] = (short)f2bf(acc);
  if (j == 0) {
    float s = b0[i] + b1[i] + b2[i];
    for (int k = 0; k < 256; ++k) s = fmaf(w1[i * 256 + k], b0[k], s);
    bc[i] = s;
  }
}

// Projection: C[i][j] = sum_k x[i][k]*W[j][k] + bias[j], A fp32 staged in LDS.
// BM=128, BN=256, BK=64, 8 waves (2M x 4N). grid.y selects view.
__global__ __launch_bounds__(512) void proj_k(
    const float* __restrict__ Af0, const float* __restrict__ Af1,
    const short* __restrict__ Bw0, const short* __restrict__ Bw1,
    const float* __restrict__ bi0, const float* __restrict__ bi1,
    short* __restrict__ Cb0, short* __restrict__ Cb1)
{
  const float* Af = blockIdx.y ? Af1 : Af0;
  const short* Bw = blockIdx.y ? Bw1 : Bw0;
  const float* bias = blockIdx.y ? bi1 : bi0;
  short* Cb = blockIdx.y ? Cb1 : Cb0;

  __shared__ __align__(16) char BsRaw[256 * 64 * 2];   // 32 KB, XOR-swizzled
  __shared__ __align__(16) char AsRaw[128 * 64 * 4];   // 32 KB fp32

  const int tid = threadIdx.x;
  const int lane = tid & 63;
  const int wave = tid >> 6;
  const int wr = wave >> 2;
  const int wc = wave & 3;
  const int row0 = blockIdx.x * 128;

  float4v acc[4][4];
#pragma unroll
  for (int m = 0; m < 4; ++m)
#pragma unroll
    for (int n = 0; n < 4; ++n) acc[m][n] = (float4v)0.f;

  for (int k0 = 0; k0 < DD; k0 += 64) {
#pragma unroll
    for (int q = 0; q < 4; ++q) {
      int ch = q * 512 + tid;
      int r = ch >> 3, pc = ch & 7;
      int lc = pc ^ (r & 7);
      GLOAD16(Bw + (size_t)r * DD + k0 + lc * 8, BsRaw + (q * 512 + wave * 64) * 16);
    }
#pragma unroll
    for (int q = 0; q < 4; ++q) {
      int ch = q * 512 + tid;
      int r = ch >> 4, pc = ch & 15;
      int lc = pc ^ (r & 15);
      int rg = min(row0 + r, NN - 1);
      GLOAD16(Af + (size_t)rg * DD + k0 + lc * 4, AsRaw + (q * 512 + wave * 64) * 16);
    }
    __syncthreads();

#pragma unroll
    for (int kk = 0; kk < 2; ++kk) {
      const int ckb = kk * 4 + (lane >> 4);
      short8v a[4], b[4];
#pragma unroll
      for (int n = 0; n < 4; ++n) {
        int rb = wc * 64 + n * 16 + (lane & 15);
        b[n] = *reinterpret_cast<const short8v*>(BsRaw + rb * 128 + ((ckb ^ (rb & 7)) << 4));
      }
#pragma unroll
      for (int m = 0; m < 4; ++m) {
        int ra = wr * 64 + m * 16 + (lane & 15);
        int ck0 = kk * 8 + (lane >> 4) * 2;
        float4v f0 = *reinterpret_cast<const float4v*>(AsRaw + ra * 256 + ((ck0 ^ (ra & 15)) << 4));
        float4v f1 = *reinterpret_cast<const float4v*>(AsRaw + ra * 256 + (((ck0 + 1) ^ (ra & 15)) << 4));
        short8v av;
        av[0] = (short)f2bf(f0[0]); av[1] = (short)f2bf(f0[1]);
        av[2] = (short)f2bf(f0[2]); av[3] = (short)f2bf(f0[3]);
        av[4] = (short)f2bf(f1[0]); av[5] = (short)f2bf(f1[1]);
        av[6] = (short)f2bf(f1[2]); av[7] = (short)f2bf(f1[3]);
        a[m] = av;
      }
#pragma unroll
      for (int m = 0; m < 4; ++m)
#pragma unroll
        for (int n = 0; n < 4; ++n)
          acc[m][n] = __builtin_amdgcn_mfma_f32_16x16x32_bf16(b[n], a[m], acc[m][n], 0, 0, 0);
    }
    __syncthreads();
  }

  const int crow = lane & 15;
  const int cg = (lane >> 4) * 4;
#pragma unroll
  for (int m = 0; m < 4; ++m) {
    int rg = row0 + wr * 64 + m * 16 + crow;
    if (rg >= NN) continue;
#pragma unroll
    for (int n = 0; n < 4; ++n) {
      int colb = wc * 64 + n * 16 + cg;
      size_t off = (size_t)rg * HH + colb;
      float4v bi = *reinterpret_cast<const float4v*>(bias + colb);
      short4v o;
#pragma unroll
      for (int i = 0; i < 4; ++i) o[i] = (short)f2bf(acc[m][n][i] + bi[i]);
      *reinterpret_cast<short4v*>(Cb + off) = o;
    }
  }
}

// Dual-view fused epoch: block owns rows [row0, row0+64) of BOTH views.
// Waves 0-3: view0, waves 4-7: view1. B tile (Bcat, shared) staged once per step.
// Per view: h' = Bcat . [Dv ; mean_j Dv[nbrv] ; Cv] + bc
// EPI 0: write O0/O1 bf16.  EPI 1: relu both, in-block average -> Of fp32.
template<int EPI>
__global__ __launch_bounds__(512) void epoch_dual(
    const short* __restrict__ D0, const short* __restrict__ D1,
    const short* __restrict__ C0, const short* __restrict__ C1,
    const short* __restrict__ Bw, const float* __restrict__ bias,
    short* __restrict__ O0, short* __restrict__ O1, float* __restrict__ Of,
    const int* __restrict__ nbr0, const int* __restrict__ nbr1)
{
  __shared__ __align__(16) char BsRaw[256 * 64 * 2];  // 32 KB (aliased as XBuf in EPI=1 epilogue)
  __shared__ __align__(16) char A0Raw[64 * 64 * 2];   // 8 KB
  __shared__ __align__(16) char A1Raw[64 * 64 * 2];   // 8 KB
  __shared__ int nbrL[2][64][KNB];                    // 2.5 KB

  const int tid = threadIdx.x;
  const int lane = tid & 63;
  const int wave = tid >> 6;
  const int vv = wave >> 2;      // view of this wave
  const int wc = wave & 3;       // N quadrant
  const int row0 = blockIdx.x * 64;

  // preload both views' neighbor indices (first use is step 4; barriers intervene)
  for (int e = tid; e < 2 * 64 * KNB; e += 512) {
    int v = e / (64 * KNB);
    int r = (e / KNB) & 63;
    int rg = min(row0 + r, NN - 1);
    const int* nb = v ? nbr1 : nbr0;
    nbrL[v][r][e % KNB] = nb[rg * KNB + (e % KNB)];
  }

  float4v acc[4][4];
#pragma unroll
  for (int m = 0; m < 4; ++m)
#pragma unroll
    for (int n = 0; n < 4; ++n) acc[m][n] = (float4v)0.f;

  for (int s = 0; s < 12; ++s) {
    const int k0 = s * 64;
    // ---- stage B [256][64]: 2048 chunks, 4/thread, pre-swizzled source ----
#pragma unroll
    for (int q = 0; q < 4; ++q) {
      int ch = q * 512 + tid;
      int r = ch >> 3, pc = ch & 7;
      int lc = pc ^ (r & 7);
      GLOAD16(Bw + (size_t)r * 768 + k0 + lc * 8, BsRaw + (q * 512 + wave * 64) * 16);
    }
    // ---- stage A0/A1 [64][64]: 512 chunks each, 1/thread ----
    {
      int ch = tid;
      int r = ch >> 3, pc = ch & 7;
      int lc = pc ^ (r & 7);
      if (s < 4 || s >= 8) {
        const short* S0 = (s < 4) ? (D0 + k0) : (C0 + (k0 - 512));
        const short* S1 = (s < 4) ? (D1 + k0) : (C1 + (k0 - 512));
        int rg = min(row0 + r, NN - 1);
        GLOAD16(S0 + (size_t)rg * HH + lc * 8, A0Raw + (wave * 64) * 16);
        GLOAD16(S1 + (size_t)rg * HH + lc * 8, A1Raw + (wave * 64) * 16);
      } else {
        const int kb = k0 - 256;
        float a0[8] = {0.f,0.f,0.f,0.f,0.f,0.f,0.f,0.f};
        float a1[8] = {0.f,0.f,0.f,0.f,0.f,0.f,0.f,0.f};
#pragma unroll
        for (int j = 0; j < KNB; ++j) {
          int id0 = nbrL[0][r][j];
          int id1 = nbrL[1][r][j];
          short8v v0 = *reinterpret_cast<const short8v*>(D0 + (size_t)id0 * HH + kb + lc * 8);
          short8v v1 = *reinterpret_cast<const short8v*>(D1 + (size_t)id1 * HH + kb + lc * 8);
#pragma unroll
          for (int x = 0; x < 8; ++x) {
            a0[x] += bf2f((unsigned short)v0[x]);
            a1[x] += bf2f((unsigned short)v1[x]);
          }
        }
        short8v o0, o1;
#pragma unroll
        for (int x = 0; x < 8; ++x) {
          o0[x] = (short)f2bf(a0[x] * 0.2f);
          o1[x] = (short)f2bf(a1[x] * 0.2f);
        }
        *reinterpret_cast<short8v*>(A0Raw + ch * 16) = o0;
        *reinterpret_cast<short8v*>(A1Raw + ch * 16) = o1;
      }
    }
    __syncthreads();

    // ---- compute: each wave 64x64 of its view ----
    const char* Asrc = vv ? A1Raw : A0Raw;
#pragma unroll
    for (int kk = 0; kk < 2; ++kk) {
      const int ckb = kk * 4 + (lane >> 4);
      short8v a[4], b[4];
#pragma unroll
      for (int n = 0; n < 4; ++n) {
        int rb = wc * 64 + n * 16 + (lane & 15);
        b[n] = *reinterpret_cast<const short8v*>(BsRaw + rb * 128 + ((ckb ^ (rb & 7)) << 4));
      }
#pragma unroll
      for (int m = 0; m < 4; ++m) {
        int ra = m * 16 + (lane & 15);
        a[m] = *reinterpret_cast<const short8v*>(Asrc + ra * 128 + ((ckb ^ (ra & 7)) << 4));
      }
#pragma unroll
      for (int m = 0; m < 4; ++m)
#pragma unroll
        for (int n = 0; n < 4; ++n)
          acc[m][n] = __builtin_amdgcn_mfma_f32_16x16x32_bf16(b[n], a[m], acc[m][n], 0, 0, 0);
          // swapped operands: lane row = lane&15, 4 consecutive cols = (lane>>4)*4..+3
    }
    __syncthreads();
  }

  // ---- epilogue ----
  const int crow = lane & 15;
  const int cg = (lane >> 4) * 4;
  if constexpr (EPI == 0) {
    short* O = vv ? O1 : O0;
#pragma unroll
    for (int m = 0; m < 4; ++m) {
      int rg = row0 + m * 16 + crow;
      if (rg >= NN) continue;
#pragma unroll
      for (int n = 0; n < 4; ++n) {
        int colb = wc * 64 + n * 16 + cg;
        float4v bi = *reinterpret_cast<const float4v*>(bias + colb);
        short4v o;
#pragma unroll
        for (int i = 0; i < 4; ++i) o[i] = (short)f2bf(acc[m][n][i] + bi[i]);
        *reinterpret_cast<short4v*>(O + (size_t)rg * HH + colb) = o;
      }
    }
  } else {
    // view0 -> relu -> bf16 into XBuf (aliases BsRaw, 64x256 bf16 = 32 KB, row-XOR swizzled)
    if (vv == 0) {
#pragma unroll
      for (int m = 0; m < 4; ++m) {
        int rl = m * 16 + crow;
#pragma unroll
        for (int n = 0; n < 4; ++n) {
          int colb = wc * 64 + n * 16 + cg;
          float4v bi = *reinterpret_cast<const float4v*>(bias + colb);
          short4v o;
#pragma unroll
          for (int i = 0; i < 4; ++i) o[i] = (short)f2bf(fmaxf(acc[m][n][i] + bi[i], 0.f));
          int c8 = (colb >> 2) ^ (rl & 7);
          *reinterpret_cast<short4v*>(BsRaw + rl * 512 + c8 * 8) = o;
        }
      }
    }
    __syncthreads();
    if (vv == 1) {
#pragma unroll
      for (int m = 0; m < 4; ++m) {
        int rl = m * 16 + crow;
        int rg = row0 + rl;
        if (rg >= NN) continue;
#pragma unroll
        for (int n = 0; n < 4; ++n) {
          int colb = wc * 64 + n * 16 + cg;
          float4v bi = *reinterpret_cast<const float4v*>(bias + colb);
          int c8 = (colb >> 2) ^ (rl & 7);
          short4v x4 = *reinterpret_cast<const short4v*>(BsRaw + rl * 512 + c8 * 8);
          float4v o;
#pragma unroll
          for (int i = 0; i < 4; ++i)
            o[i] = (fmaxf(acc[m][n][i] + bi[i], 0.f) + bf2f((unsigned short)x4[i])) * 0.5f;
          *reinterpret_cast<float4v*>(Of + (size_t)rg * HH + colb) = o;
        }
      }
    }
  }
}

extern "C" void kernel_launch(void* const* d_in, const int* in_sizes, int n_in,
                              void* d_out, int out_size, void* d_ws, size_t ws_size,
                              hipStream_t stream) {
  const float* x0  = (const float*)d_in[0];
  const float* x1  = (const float*)d_in[1];
  const float* wh0 = (const float*)d_in[2];
  const float* bh0 = (const float*)d_in[3];
  const float* wh1 = (const float*)d_in[4];
  const float* bh1 = (const float*)d_in[5];
  const float* w0  = (const float*)d_in[6];
  const float* b0  = (const float*)d_in[7];
  const float* w1  = (const float*)d_in[8];
  const float* b1  = (const float*)d_in[9];
  const float* w2  = (const float*)d_in[10];
  const float* b2  = (const float*)d_in[11];
  const int* e0    = (const int*)d_in[12];
  const int* e1    = (const int*)d_in[13];
  const int* nbr0  = e0 + (size_t)NN * KNB;  // edge[1]
  const int* nbr1  = e1 + (size_t)NN * KNB;
  float* out       = (float*)d_out;

  char* ws = (char*)d_ws;
  size_t off = 0;
  auto alloc = [&](size_t bytes) -> void* {
    off = (off + 255) & ~(size_t)255;
    void* p = ws + off;
    off += bytes;
    return p;
  };

  short* Wh0  = (short*)alloc((size_t)HH * DD * 2);
  short* Wh1  = (short*)alloc((size_t)HH * DD * 2);
  short* Bcat = (short*)alloc((size_t)HH * 768 * 2);
  float* bc   = (float*)alloc((size_t)HH * 4);
  const size_t NB = (size_t)NN * HH * 2;
  short* hi0 = (short*)alloc(NB);
  short* hi1 = (short*)alloc(NB);
  short* hb0 = (short*)alloc(NB);
  short* hb1 = (short*)alloc(NB);

  // weight prep
  cvt2<<<dim3(256), dim3(256), 0, stream>>>(wh0, Wh0, wh1, Wh1);
  prep_w01<<<dim3(256), dim3(256), 0, stream>>>(w0, w1, w2, b0, b1, b2, Bcat, bc);

  // both projections in one launch
  proj_k<<<dim3((NN + 127) / 128, 2), dim3(512), 0, stream>>>(
      x0, x1, Wh0, Wh1, bh0, bh1, hi0, hi1);

  dim3 ge((NN + 63) / 64);  // 1563 blocks

  // epoch 1 (both views): hb_v = Bcat.[hi_v ; gmean(hi_v) ; hi_{1-v}] + bc
  epoch_dual<0><<<ge, dim3(512), 0, stream>>>(
      hi0, hi1, hi1, hi0, Bcat, bc, hb0, hb1, nullptr, nbr0, nbr1);

  // epoch 2 (both views) + relu + in-block average -> out fp32
  epoch_dual<1><<<ge, dim3(512), 0, stream>>>(
      hb0, hb1, hi1, hi0, Bcat, bc, nullptr, nullptr, out, nbr0, nbr1);

  (void)in_sizes; (void)n_in; (void)out_size; (void)ws_size;
}